// Round 3
// baseline (157.114 us; speedup 1.0000x reference)
//
#include <hip/hip_runtime.h>

// Trilinear interp of [64,64,64,64] fp32 volume at 200k random points.
// R3: Morton counting-sort kept; scan rewritten shuffle-based (2 barriers
// instead of 20); gather output stores are nontemporal (51MB streamed, no
// reuse -> keep L2 for gather data).

#define NBINS 32768          // 32^3 Morton bins of 2^3 voxels

typedef float  __attribute__((ext_vector_type(4))) fx4;

__device__ __forceinline__ float4 f4mul(float4 a, float s) {
    return make_float4(a.x * s, a.y * s, a.z * s, a.w * s);
}
__device__ __forceinline__ float4 f4fma(float4 a, float s, float4 acc) {
    return make_float4(fmaf(a.x, s, acc.x), fmaf(a.y, s, acc.y),
                       fmaf(a.z, s, acc.z), fmaf(a.w, s, acc.w));
}

__device__ __forceinline__ unsigned part1by2(unsigned x) {
    x &= 0x3FF;
    x = (x | (x << 16)) & 0x030000FF;
    x = (x | (x << 8))  & 0x0300F00F;
    x = (x | (x << 4))  & 0x030C30C3;
    x = (x | (x << 2))  & 0x09249249;
    return x;
}

__device__ __forceinline__ int bin_of(float xs, float ys, float zs) {
    unsigned bx = ((unsigned)(int)floorf(xs)) >> 1;   // 0..31
    unsigned by = ((unsigned)(int)floorf(ys)) >> 1;
    unsigned bz = ((unsigned)(int)floorf(zs)) >> 1;
    return (int)(part1by2(bx) | (part1by2(by) << 1) | (part1by2(bz) << 2));
}

__global__ __launch_bounds__(256) void hist_kernel(
    const float* __restrict__ coords, int* __restrict__ bins, int n)
{
    int p = blockIdx.x * 256 + threadIdx.x;
    if (p >= n) return;
    float xs = coords[3 * p + 0] * 0.5f;
    float ys = coords[3 * p + 1] * 0.5f;
    float zs = coords[3 * p + 2] * 0.5f;
    atomicAdd(&bins[bin_of(xs, ys, zs)], 1);
}

// 1024 threads x 32 bins each = 32768. Shuffle-based hierarchical scan:
// serial(32) -> wave shfl_up(64) -> 16 wave-sums in LDS -> broadcast.
__global__ __launch_bounds__(1024) void scan_kernel(int* __restrict__ bins)
{
    __shared__ int wsum[16];
    int t = threadIdx.x;
    int w = t >> 6, lane = t & 63;

    int local[32];
    {
        const int4* b4 = (const int4*)bins + t * 8;
        int4 v[8];
        #pragma unroll
        for (int i = 0; i < 8; i++) v[i] = b4[i];
        const int* lp = (const int*)v;
        #pragma unroll
        for (int i = 0; i < 32; i++) local[i] = lp[i];
    }
    int tsum = 0;
    #pragma unroll
    for (int i = 0; i < 32; i++) { int v = local[i]; local[i] = tsum; tsum += v; }

    // inclusive wave scan of tsum
    int incl = tsum;
    #pragma unroll
    for (int off = 1; off < 64; off <<= 1) {
        int u = __shfl_up(incl, off);
        if (lane >= off) incl += u;
    }
    if (lane == 63) wsum[w] = incl;
    __syncthreads();
    if (t < 16) {
        int x = wsum[t];
        int xin = x;
        #pragma unroll
        for (int off = 1; off < 16; off <<= 1) {
            int u = __shfl_up(xin, off);
            if (t >= off) xin += u;
        }
        wsum[t] = xin - x;   // exclusive wave prefix
    }
    __syncthreads();

    int prefix = wsum[w] + (incl - tsum);   // exclusive prefix of this thread
    {
        int4* b4 = (int4*)bins + t * 8;
        int4 v[8];
        int* lp = (int*)v;
        #pragma unroll
        for (int i = 0; i < 32; i++) lp[i] = local[i] + prefix;
        #pragma unroll
        for (int i = 0; i < 8; i++) b4[i] = v[i];
    }
}

__global__ __launch_bounds__(256) void scatter_kernel(
    const float* __restrict__ coords, int* __restrict__ offs,
    float4* __restrict__ coordsS, int n)
{
    int p = blockIdx.x * 256 + threadIdx.x;
    if (p >= n) return;
    float xs = coords[3 * p + 0] * 0.5f;
    float ys = coords[3 * p + 1] * 0.5f;
    float zs = coords[3 * p + 2] * 0.5f;
    int r = atomicAdd(&offs[bin_of(xs, ys, zs)], 1);
    coordsS[r] = make_float4(xs, ys, zs, __int_as_float(p));
}

__global__ __launch_bounds__(256) void trilerp_sorted_kernel(
    const float* __restrict__ img, const float4* __restrict__ coordsS,
    float* __restrict__ out, int n_points, int per_xcd)
{
    int b = (blockIdx.x & 7) * per_xcd + (blockIdx.x >> 3);
    int tid = b * 256 + threadIdx.x;
    int sp = tid >> 4;
    if (sp >= n_points) return;
    int cvec = tid & 15;

    float4 cs = coordsS[sp];
    float x = cs.x, y = cs.y, z = cs.z;
    int p = __float_as_int(cs.w);

    float fx1 = floorf(x), fx2 = fminf(ceilf(x), 63.0f);
    float fy1 = floorf(y), fy2 = fminf(ceilf(y), 63.0f);
    float fz1 = floorf(z), fz2 = fminf(ceilf(z), 63.0f);

    float wx = x - fx1, wxc = fx2 - x;
    float wy = y - fy1, wyc = fy2 - y;
    float wz = z - fz1, wzc = fz2 - z;

    int ix1 = (int)fx1, ix2 = (int)fx2;
    int iy1 = (int)fy1, iy2 = (int)fy2;
    int iz1 = (int)fz1, iz2 = (int)fz2;

    const float4* __restrict__ imgv = (const float4*)img;
    int bx1 = ix1 << 12, bx2 = ix2 << 12;
    int by1 = iy1 << 6,  by2 = iy2 << 6;

    float4 q11 = imgv[((bx1 + by1 + iz1) << 4) + cvec];
    float4 q21 = imgv[((bx2 + by1 + iz1) << 4) + cvec];
    float4 q12 = imgv[((bx1 + by2 + iz1) << 4) + cvec];
    float4 q22 = imgv[((bx2 + by2 + iz1) << 4) + cvec];
    float4 ly1 = f4fma(f4fma(q22, wx, f4mul(q12, wxc)), wy,
                       f4mul(f4fma(q21, wx, f4mul(q11, wxc)), wyc));

    q11 = imgv[((bx1 + by1 + iz2) << 4) + cvec];
    q21 = imgv[((bx2 + by1 + iz2) << 4) + cvec];
    q12 = imgv[((bx1 + by2 + iz2) << 4) + cvec];
    q22 = imgv[((bx2 + by2 + iz2) << 4) + cvec];
    float4 ly2 = f4fma(f4fma(q22, wx, f4mul(q12, wxc)), wy,
                       f4mul(f4fma(q21, wx, f4mul(q11, wxc)), wyc));

    float4 res = f4fma(ly2, wz, f4mul(ly1, wzc));

    fx4 r; r.x = res.x; r.y = res.y; r.z = res.z; r.w = res.w;
    __builtin_nontemporal_store(r, (fx4*)out + (p << 4) + cvec);
}

// Fallback (R1 kernel) if workspace too small.
__global__ __launch_bounds__(256) void trilerp_kernel(
    const float* __restrict__ img, const float* __restrict__ coords,
    float* __restrict__ out, int n_points)
{
    int tid = blockIdx.x * 256 + threadIdx.x;
    int p = tid >> 4;
    if (p >= n_points) return;
    int cvec = tid & 15;

    float x = coords[3 * p + 0] * 0.5f;
    float y = coords[3 * p + 1] * 0.5f;
    float z = coords[3 * p + 2] * 0.5f;

    float fx1 = floorf(x), fx2 = fminf(ceilf(x), 63.0f);
    float fy1 = floorf(y), fy2 = fminf(ceilf(y), 63.0f);
    float fz1 = floorf(z), fz2 = fminf(ceilf(z), 63.0f);

    float wx = x - fx1, wxc = fx2 - x;
    float wy = y - fy1, wyc = fy2 - y;
    float wz = z - fz1, wzc = fz2 - z;

    int ix1 = (int)fx1, ix2 = (int)fx2;
    int iy1 = (int)fy1, iy2 = (int)fy2;
    int iz1 = (int)fz1, iz2 = (int)fz2;

    const float4* __restrict__ imgv = (const float4*)img;
    int bx1 = ix1 << 12, bx2 = ix2 << 12;
    int by1 = iy1 << 6,  by2 = iy2 << 6;

    float4 q11 = imgv[((bx1 + by1 + iz1) << 4) + cvec];
    float4 q21 = imgv[((bx2 + by1 + iz1) << 4) + cvec];
    float4 q12 = imgv[((bx1 + by2 + iz1) << 4) + cvec];
    float4 q22 = imgv[((bx2 + by2 + iz1) << 4) + cvec];
    float4 ly1 = f4fma(f4fma(q22, wx, f4mul(q12, wxc)), wy,
                       f4mul(f4fma(q21, wx, f4mul(q11, wxc)), wyc));

    q11 = imgv[((bx1 + by1 + iz2) << 4) + cvec];
    q21 = imgv[((bx2 + by1 + iz2) << 4) + cvec];
    q12 = imgv[((bx1 + by2 + iz2) << 4) + cvec];
    q22 = imgv[((bx2 + by2 + iz2) << 4) + cvec];
    float4 ly2 = f4fma(f4fma(q22, wx, f4mul(q12, wxc)), wy,
                       f4mul(f4fma(q21, wx, f4mul(q11, wxc)), wyc));

    float4 res = f4fma(ly2, wz, f4mul(ly1, wzc));
    ((float4*)out)[(p << 4) + cvec] = res;
}

extern "C" void kernel_launch(void* const* d_in, const int* in_sizes, int n_in,
                              void* d_out, int out_size, void* d_ws, size_t ws_size,
                              hipStream_t stream) {
    const float* img    = (const float*)d_in[0];   // [1,64,64,64,64]
    const float* coords = (const float*)d_in[1];   // [1,N,3]
    float* out = (float*)d_out;                    // [1,N,64]
    int n = in_sizes[1] / 3;

    size_t bins_bytes  = (size_t)NBINS * sizeof(int);
    size_t coordsS_off = bins_bytes;
    size_t need = coordsS_off + (size_t)n * sizeof(float4);

    if (ws_size >= need) {
        int* bins       = (int*)d_ws;
        float4* coordsS = (float4*)((char*)d_ws + coordsS_off);

        hipMemsetAsync(bins, 0, bins_bytes, stream);

        int pgrid = (n + 255) / 256;
        hist_kernel<<<pgrid, 256, 0, stream>>>(coords, bins, n);
        scan_kernel<<<1, 1024, 0, stream>>>(bins);
        scatter_kernel<<<pgrid, 256, 0, stream>>>(coords, bins, coordsS, n);

        int threads = n * 16;
        int nb = (threads + 255) / 256;
        int nb_pad = (nb + 7) & ~7;
        int per_xcd = nb_pad >> 3;
        trilerp_sorted_kernel<<<nb_pad, 256, 0, stream>>>(img, coordsS, out, n, per_xcd);
    } else {
        int threads = n * 16;
        int grid = (threads + 255) / 256;
        trilerp_kernel<<<grid, 256, 0, stream>>>(img, coords, out, n);
    }
}

// Round 4
// 146.755 us; speedup vs baseline: 1.0706x; 1.0706x over previous
//
#include <hip/hip_runtime.h>

// Trilinear interp of [64,64,64,64] fp32 volume at 200k points.
// R4: back to the sort-free single kernel (R2/R3 showed the 4-kernel Morton
// sort costs ~32us to save ~23us on the gather). Attack latency-boundness
// with ILP instead: 2 points per thread -> 16 corner loads in flight.
// Wave covers 8 points: lanes (sub=lane>>4, cvec=lane&15); point A = base+sub,
// point B = base+4+sub, so each of the two output stores is a contiguous
// 4KB wave-store. Output stores nontemporal (51MB streamed, zero reuse).

typedef float __attribute__((ext_vector_type(4))) fx4;

__device__ __forceinline__ float4 f4mul(float4 a, float s) {
    return make_float4(a.x * s, a.y * s, a.z * s, a.w * s);
}
__device__ __forceinline__ float4 f4fma(float4 a, float s, float4 acc) {
    return make_float4(fmaf(a.x, s, acc.x), fmaf(a.y, s, acc.y),
                       fmaf(a.z, s, acc.z), fmaf(a.w, s, acc.w));
}

__global__ __launch_bounds__(256) void trilerp2_kernel(
    const float* __restrict__ img, const float* __restrict__ coords,
    float* __restrict__ out, int n_points)
{
    int tid  = blockIdx.x * 256 + threadIdx.x;
    int wave = tid >> 6;            // global wave id; wave covers 8 points
    int lane = tid & 63;
    int sub  = lane >> 4;           // 0..3
    int cvec = lane & 15;           // which float4 of 64 channels

    int pA = wave * 8 + sub;        // first point
    int pB = pA + 4;                // second point
    if (pA >= n_points) return;
    bool hasB = (pB < n_points);

    // ---- point A address/weight setup ----
    float xA = coords[3 * pA + 0] * 0.5f;
    float yA = coords[3 * pA + 1] * 0.5f;
    float zA = coords[3 * pA + 2] * 0.5f;
    // ---- point B (clamp index so loads are safe; store predicated) ----
    int pBs = hasB ? pB : pA;
    float xB = coords[3 * pBs + 0] * 0.5f;
    float yB = coords[3 * pBs + 1] * 0.5f;
    float zB = coords[3 * pBs + 2] * 0.5f;

    float fx1A = floorf(xA), fx2A = fminf(ceilf(xA), 63.0f);
    float fy1A = floorf(yA), fy2A = fminf(ceilf(yA), 63.0f);
    float fz1A = floorf(zA), fz2A = fminf(ceilf(zA), 63.0f);
    float fx1B = floorf(xB), fx2B = fminf(ceilf(xB), 63.0f);
    float fy1B = floorf(yB), fy2B = fminf(ceilf(yB), 63.0f);
    float fz1B = floorf(zB), fz2B = fminf(ceilf(zB), 63.0f);

    const float4* __restrict__ imgv = (const float4*)img;
    // float4 index: (((x<<6)+y)<<6 + z)*16 + cvec
    int bx1A = ((int)fx1A) << 12, bx2A = ((int)fx2A) << 12;
    int by1A = ((int)fy1A) << 6,  by2A = ((int)fy2A) << 6;
    int iz1A = (int)fz1A,         iz2A = (int)fz2A;
    int bx1B = ((int)fx1B) << 12, bx2B = ((int)fx2B) << 12;
    int by1B = ((int)fy1B) << 6,  by2B = ((int)fy2B) << 6;
    int iz1B = (int)fz1B,         iz2B = (int)fz2B;

    // ---- issue all 16 corner loads (independent -> 16 outstanding) ----
    float4 a111 = imgv[((bx1A + by1A + iz1A) << 4) + cvec];
    float4 a211 = imgv[((bx2A + by1A + iz1A) << 4) + cvec];
    float4 a121 = imgv[((bx1A + by2A + iz1A) << 4) + cvec];
    float4 a221 = imgv[((bx2A + by2A + iz1A) << 4) + cvec];
    float4 a112 = imgv[((bx1A + by1A + iz2A) << 4) + cvec];
    float4 a212 = imgv[((bx2A + by1A + iz2A) << 4) + cvec];
    float4 a122 = imgv[((bx1A + by2A + iz2A) << 4) + cvec];
    float4 a222 = imgv[((bx2A + by2A + iz2A) << 4) + cvec];
    float4 b111 = imgv[((bx1B + by1B + iz1B) << 4) + cvec];
    float4 b211 = imgv[((bx2B + by1B + iz1B) << 4) + cvec];
    float4 b121 = imgv[((bx1B + by2B + iz1B) << 4) + cvec];
    float4 b221 = imgv[((bx2B + by2B + iz1B) << 4) + cvec];
    float4 b112 = imgv[((bx1B + by1B + iz2B) << 4) + cvec];
    float4 b212 = imgv[((bx2B + by1B + iz2B) << 4) + cvec];
    float4 b122 = imgv[((bx1B + by2B + iz2B) << 4) + cvec];
    float4 b222 = imgv[((bx2B + by2B + iz2B) << 4) + cvec];

    // ---- point A math ----
    float wxA = xA - fx1A, wxcA = fx2A - xA;
    float wyA = yA - fy1A, wycA = fy2A - yA;
    float wzA = zA - fz1A, wzcA = fz2A - zA;
    float4 ly1A = f4fma(f4fma(a221, wxA, f4mul(a121, wxcA)), wyA,
                        f4mul(f4fma(a211, wxA, f4mul(a111, wxcA)), wycA));
    float4 ly2A = f4fma(f4fma(a222, wxA, f4mul(a122, wxcA)), wyA,
                        f4mul(f4fma(a212, wxA, f4mul(a112, wxcA)), wycA));
    float4 resA = f4fma(ly2A, wzA, f4mul(ly1A, wzcA));
    fx4 rA; rA.x = resA.x; rA.y = resA.y; rA.z = resA.z; rA.w = resA.w;
    __builtin_nontemporal_store(rA, (fx4*)out + (pA << 4) + cvec);

    // ---- point B math ----
    if (hasB) {
        float wxB = xB - fx1B, wxcB = fx2B - xB;
        float wyB = yB - fy1B, wycB = fy2B - yB;
        float wzB = zB - fz1B, wzcB = fz2B - zB;
        float4 ly1B = f4fma(f4fma(b221, wxB, f4mul(b121, wxcB)), wyB,
                            f4mul(f4fma(b211, wxB, f4mul(b111, wxcB)), wycB));
        float4 ly2B = f4fma(f4fma(b222, wxB, f4mul(b122, wxcB)), wyB,
                            f4mul(f4fma(b212, wxB, f4mul(b112, wxcB)), wycB));
        float4 resB = f4fma(ly2B, wzB, f4mul(ly1B, wzcB));
        fx4 rB; rB.x = resB.x; rB.y = resB.y; rB.z = resB.z; rB.w = resB.w;
        __builtin_nontemporal_store(rB, (fx4*)out + (pB << 4) + cvec);
    }
}

extern "C" void kernel_launch(void* const* d_in, const int* in_sizes, int n_in,
                              void* d_out, int out_size, void* d_ws, size_t ws_size,
                              hipStream_t stream) {
    const float* img    = (const float*)d_in[0];   // [1,64,64,64,64]
    const float* coords = (const float*)d_in[1];   // [1,N,3]
    float* out = (float*)d_out;                    // [1,N,64]
    int n = in_sizes[1] / 3;

    // one wave per 8 points
    int waves = (n + 7) / 8;
    int threads = waves * 64;
    int grid = (threads + 255) / 256;
    trilerp2_kernel<<<grid, 256, 0, stream>>>(img, coords, out, n);
}